// Round 22
// baseline (47.709 us; speedup 1.0000x reference)
//
#include <hip/hip_runtime.h>
#include <cstdint>
#include <cstddef>

#define BB 16
#define AA 8400
#define CC 80
#define MM 32
#define TOPK 13
#define NW 8                 // waves (chunks) per row-block
#define CANCH 1056           // anchors per wave-chunk (8*1056 = 8448 >= AA)

// Shared CIoU (clipped) so every use site has the identical formula.
__device__ __forceinline__ float ciou_clip(
    float gx1, float gy1, float gx2, float gy2, float at1,
    float4 pb, float w2, float h2, float at2)
{
  const float w1 = gx2 - gx1, h1 = gy2 - gy1 + 1e-7f;
  const float iw = fmaxf(fminf(gx2, pb.z) - fmaxf(gx1, pb.x), 0.f);
  const float ih = fmaxf(fminf(gy2, pb.w) - fmaxf(gy1, pb.y), 0.f);
  const float inter = iw * ih;
  const float uni = w1*h1 + w2*h2 - inter + 1e-7f;
  const float iou = inter / uni;
  const float cw = fmaxf(gx2, pb.z) - fminf(gx1, pb.x);
  const float ch = fmaxf(gy2, pb.w) - fminf(gy1, pb.y);
  const float c2 = cw*cw + ch*ch + 1e-7f;
  const float rx = pb.x + pb.z - gx1 - gx2;
  const float ry = pb.y + pb.w - gy1 - gy2;
  const float rho2 = (rx*rx + ry*ry) * 0.25f;
  const float dv = at2 - at1;
  const float v = 0.4052847345693511f * dv * dv;
  const float alpha = v / (v - iou + (1.f + 1e-7f));
  return fmaxf(iou - (rho2 / c2 + v * alpha), 0.f);
}

// (val desc, idx asc) as one monotone u64 key; val >= 0 so float bits are
// order-preserving. Sentinel/empty = 0 (loses to every real entry; decodes
// to anchor -1 — ALL decode sites must use unsigned bounds checks).
__device__ __forceinline__ unsigned long long pack_key(float val, int a) {
  return ((unsigned long long)__float_as_uint(val) << 32)
       | (unsigned long long)(0xFFFFFFFFu - (unsigned)a);
}
__device__ __forceinline__ int key_anchor(unsigned long long k) {
  return (int)(0xFFFFFFFFu - (unsigned)(k & 0xFFFFFFFFull));
}

// ---------------------------------------------------------------------------
// K1: per-(b,m) block (8 waves, 512 thr): own mind-test scan -> LDS queue ->
// dense CIoU eval -> per-lane top-13 u64 keys -> per-wave butterfly extract
// -> wave-0 merge of 8x13 -> topkeys[b][m][13]. Masked rows: sentinel keys.
// Block (0,0) zeroes pos_align/pos_ovl (512 threads = BB*MM slots) —
// REQUIRED every call: ws is poisoned 0xAA and 0xAAAAAAAA beats any float
// bit-pattern under unsigned atomicMax (the R21 absmax=0.894 bug).
// Zero-tie fill exactness: wave 0 seeds anchors [0,64) with full evals
// (val==0 when out-of-gts; those indices are excluded from the scan);
// a row with <13 positives zero-fills from indices <64 (>=51 zeros there),
// ties resolved by ascending index — matches jax.lax.top_k exactly.
// ---------------------------------------------------------------------------
__global__ __launch_bounds__(512) void k_topk(
    const float* __restrict__ pred_cls, const float* __restrict__ pred_bbox,
    const float* __restrict__ anchors, const int* __restrict__ gt_cls,
    const float* __restrict__ gt_bbox, const float* __restrict__ mask_gt,
    unsigned long long* __restrict__ topkeys,
    unsigned int* __restrict__ pos_align, unsigned int* __restrict__ pos_ovl)
{
  const int m = blockIdx.x, b = blockIdx.y;
  const int tid = threadIdx.x;
  const int wave = tid >> 6, lane = tid & 63;

  if (blockIdx.x == 0 && blockIdx.y == 0) {     // 512 threads = BB*MM slots
    pos_align[tid] = 0u; pos_ovl[tid] = 0u;
  }

  unsigned long long* tk = topkeys + (size_t)(b*MM + m)*TOPK;
  if (mask_gt[b*MM + m] <= 0.f) {        // masked gt: sentinel row
    if (tid < TOPK) tk[tid] = 0ull;
    return;
  }

  __shared__ unsigned short q[NW][CANCH];
  __shared__ unsigned long long s_top[NW][TOPK];

  const float4 gb = reinterpret_cast<const float4*>(gt_bbox)[b*MM + m];
  const float at1 = atanf((gb.z - gb.x) / (gb.w - gb.y + 1e-7f));
  const int lbl = gt_cls[b*MM + m];
  const float*  clsbase = pred_cls + (size_t)b*AA*CC;
  const float4* pbase   = reinterpret_cast<const float4*>(pred_bbox) + (size_t)b*AA;
  const float2* axy     = reinterpret_cast<const float2*>(anchors);

  unsigned long long k13[TOPK];
  #pragma unroll
  for (int i = 0; i < TOPK; ++i) k13[i] = 0ull;

  // wave-0 seed: full eval of anchor a = lane (always a candidate)
  if (wave == 0) {
    const int a = lane;
    const float2 xy = axy[a];
    const float mind = fminf(fminf(xy.x - gb.x, xy.y - gb.y),
                             fminf(gb.z - xy.x, gb.w - xy.y));
    float val = 0.f;
    if (mind > 1e-9f) {
      const float4 pb = pbase[a];
      const float w2 = pb.z - pb.x, h2 = pb.w - pb.y + 1e-7f;
      const float at2 = atanf(w2 / h2);
      const float ov = ciou_clip(gb.x, gb.y, gb.z, gb.w, at1, pb, w2, h2, at2);
      const float o2 = ov * ov;
      val = clsbase[(size_t)a*CC + lbl] * (o2 * o2 * o2);
    }
    k13[0] = pack_key(val, a);
  }

  // mind-test scan -> queue (ascending anchor order)
  const int abase = wave * CANCH;
  int qc = 0;
  for (int s = 0; s < 17; ++s) {
    const int la = s*64 + lane;
    const int a  = abase + la;
    bool pass = false;
    if (la < CANCH && a < AA && !(wave == 0 && a < 64)) {
      const float2 xy = axy[a];
      const float mind = fminf(fminf(xy.x - gb.x, xy.y - gb.y),
                               fminf(gb.z - xy.x, gb.w - xy.y));
      pass = mind > 1e-9f;
    }
    const unsigned long long bal = __ballot(pass);
    if (pass) {
      const int pos = qc + (int)__popcll(bal & ((1ull << lane) - 1ull));
      q[wave][pos] = (unsigned short)la;
    }
    qc += (int)__popcll(bal);
  }

  // dense eval of queue (per-lane stream ascending in a; key compare exact)
  for (int k = lane; k < qc; k += 64) {
    const int a = abase + (int)q[wave][k];
    const float4 pb = pbase[a];
    const float w2 = pb.z - pb.x, h2 = pb.w - pb.y + 1e-7f;
    const float at2 = atanf(w2 / h2);
    const float ov = ciou_clip(gb.x, gb.y, gb.z, gb.w, at1, pb, w2, h2, at2);
    const float o2 = ov * ov;
    const float val = clsbase[(size_t)a*CC + lbl] * (o2 * o2 * o2);
    const unsigned long long key = pack_key(val, a);
    if (key > k13[TOPK-1]) {
      #pragma unroll
      for (int i = TOPK-1; i >= 1; --i)       // static-index shift network
        if (key > k13[i]) k13[i] = (key > k13[i-1]) ? k13[i-1] : key;
      if (key > k13[0]) k13[0] = key;
    }
  }

  // per-wave 13-round extraction (u64 butterfly max) -> LDS
  for (int r = 0; r < TOPK; ++r) {
    unsigned long long bk = k13[0];
    #pragma unroll
    for (int off = 32; off; off >>= 1) {
      const unsigned long long o = __shfl_xor(bk, off);
      if (o > bk) bk = o;
    }
    if (k13[0] == bk) {                       // unique for real keys;
      #pragma unroll                          // sentinel multi-pop harmless
      for (int i = 0; i < TOPK-1; ++i) k13[i] = k13[i+1];
      k13[TOPK-1] = 0ull;
    }
    if (lane == 0) s_top[wave][r] = bk;
  }
  __syncthreads();
  if (wave != 0) return;

  // wave-0 merge of 8x13 = 104 keys (2 static slots/lane) -> topkeys row
  unsigned long long v0 = 0ull, v1 = 0ull;
  {
    const int e0 = lane, e1 = lane + 64;
    v0 = s_top[e0/TOPK][e0%TOPK];
    if (e1 < NW*TOPK) v1 = s_top[e1/TOPK][e1%TOPK];
  }
  for (int r = 0; r < TOPK; ++r) {
    const bool s1 = v1 > v0;
    unsigned long long bk = s1 ? v1 : v0;
    const unsigned long long my = bk;
    #pragma unroll
    for (int off = 32; off; off >>= 1) {
      const unsigned long long o = __shfl_xor(bk, off);
      if (o > bk) bk = o;
    }
    if (lane == 0) tk[r] = bk;
    if (my == bk && bk != 0ull) {             // unique winner pops its slot
      if (s1) v1 = 0ull; else v0 = 0ull;
    }
  }
}

// ---------------------------------------------------------------------------
// K2: 272 blocks (b, 512-anchor window). Build LDS claim bitmap for the
// window from the batch's 416 topkeys (in-gts gate, unsigned sentinel
// guards), then resolve (fg==1 / fg>1 first-max over masked overlaps),
// write anchor_m/al + out_bbox/out_fg densely, atomicMax global pos_*.
// ---------------------------------------------------------------------------
__global__ __launch_bounds__(512) void k_resolve(
    const float* __restrict__ pred_cls, const float* __restrict__ pred_bbox,
    const float* __restrict__ anchors, const int* __restrict__ gt_cls,
    const float* __restrict__ gt_bbox, const float* __restrict__ mask_gt,
    const unsigned long long* __restrict__ topkeys,
    float* __restrict__ out_bbox, float* __restrict__ out_fg,
    int* __restrict__ anchor_m, float* __restrict__ anchor_al,
    unsigned int* __restrict__ pos_align, unsigned int* __restrict__ pos_ovl)
{
  const int b = blockIdx.x / 17, ch = blockIdx.x % 17;
  const int tid = threadIdx.x;
  const int w0 = ch * 512;                  // window [w0, w0+512)
  __shared__ unsigned int s_claim[512];     // window claim bitmap
  __shared__ float4 s_gb[MM];
  __shared__ float s_at[MM], s_mgt[MM];
  __shared__ int s_lbl[MM];

  const float2* axy = reinterpret_cast<const float2*>(anchors);

  if (tid < MM) {
    const float4 g = reinterpret_cast<const float4*>(gt_bbox)[b*MM + tid];
    s_gb[tid] = g;
    s_at[tid] = atanf((g.z - g.x) / (g.w - g.y + 1e-7f));
    s_lbl[tid] = gt_cls[b*MM + tid];
    s_mgt[tid] = mask_gt[b*MM + tid];
  }
  s_claim[tid] = 0u;
  __syncthreads();

  // claim phase: 416 keys -> window bitmap (in-gts gate here)
  if (tid < MM*TOPK) {
    const int m = tid / TOPK;
    const unsigned long long key = topkeys[(size_t)(b*MM + m)*TOPK + tid%TOPK];
    const int a = key_anchor(key);
    if ((unsigned)a < (unsigned)AA && a >= w0 && a < w0 + 512) {
      const float2 xy = axy[a];
      const float4 g = s_gb[m];
      const float mind = fminf(fminf(xy.x - g.x, xy.y - g.y),
                               fminf(g.z - xy.x, g.w - xy.y));
      if (mind > 1e-9f) atomicOr(&s_claim[a - w0], 1u << m);
    }
  }
  __syncthreads();

  const int a = w0 + tid;
  if (a >= AA) return;
  const unsigned cb = s_claim[tid];
  int asg = -1; float av = 0.f;
  if (cb != 0u) {
    const float4 pb = reinterpret_cast<const float4*>(pred_bbox)[b*AA + a];
    const float2 xy = axy[a];
    const float w2 = pb.z - pb.x, h2 = pb.w - pb.y + 1e-7f;
    const float at2 = atanf(w2 / h2);
    float bestov;
    if (__popc(cb) == 1) {
      asg = __ffs(cb) - 1;   // claimed => in-gts && mask_gt>0 already hold
      const float4 g = s_gb[asg];
      bestov = ciou_clip(g.x, g.y, g.z, g.w, s_at[asg], pb, w2, h2, at2);
    } else {
      // is_max: first argmax over ALL m of masked overlaps
      float best = -1.f; int bm = 0;
      for (int m = 0; m < MM; ++m) {
        float ov = 0.f;
        const float4 g = s_gb[m];
        const float mind = fminf(fminf(xy.x - g.x, xy.y - g.y),
                                 fminf(g.z - xy.x, g.w - xy.y));
        if (mind > 1e-9f && s_mgt[m] > 0.f)
          ov = ciou_clip(g.x, g.y, g.z, g.w, s_at[m], pb, w2, h2, at2);
        if (ov > best) { best = ov; bm = m; }   // strict > => first max
      }
      asg = bm; bestov = best;
    }
    const float o2 = bestov * bestov;
    av = pred_cls[(size_t)(b*AA + a)*CC + s_lbl[asg]] * (o2 * o2 * o2);
    atomicMax(&pos_align[b*MM + asg], __float_as_uint(av));    // >=0 floats
    atomicMax(&pos_ovl[b*MM + asg], __float_as_uint(bestov));
  }
  const int tgt = (asg >= 0) ? asg : 0;     // argmax of all-zero column = 0
  reinterpret_cast<float4*>(out_bbox)[b*AA + a] = s_gb[tgt];
  out_fg[b*AA + a] = (asg >= 0) ? 1.f : 0.f;
  anchor_m[b*AA + a] = asg;
  anchor_al[b*AA + a] = av;
}

// ---------------------------------------------------------------------------
// K3: target_cls (B,A,C) float4-coalesced: norm at the label slot, else 0.
// ---------------------------------------------------------------------------
__global__ __launch_bounds__(256) void k_cls(
    const int* __restrict__ anchor_m, const float* __restrict__ anchor_al,
    const unsigned int* __restrict__ pos_align, const unsigned int* __restrict__ pos_ovl,
    const int* __restrict__ gt_cls, float* __restrict__ out_cls)
{
  const int tid = blockIdx.x*256 + threadIdx.x;
  if (tid >= BB*AA*(CC/4)) return;
  const int q  = tid % (CC/4);
  const int ba = tid / (CC/4);
  const int b  = ba / AA;
  const int m  = anchor_m[ba];
  float4 o = make_float4(0.f, 0.f, 0.f, 0.f);
  if (m >= 0) {
    const float pa = __uint_as_float(pos_align[b*MM + m]);
    const float po = __uint_as_float(pos_ovl[b*MM + m]);
    const float norm = anchor_al[ba] * po / (pa + 1e-9f);
    const int lbl = gt_cls[b*MM + m];
    const int c0 = q * 4;
    if (lbl == c0    ) o.x = norm;
    if (lbl == c0 + 1) o.y = norm;
    if (lbl == c0 + 2) o.z = norm;
    if (lbl == c0 + 3) o.w = norm;
  }
  reinterpret_cast<float4*>(out_cls)[tid] = o;
}

// ---------------------------------------------------------------------------
extern "C" void kernel_launch(void* const* d_in, const int* in_sizes, int n_in,
                              void* d_out, int out_size, void* d_ws, size_t ws_size,
                              hipStream_t stream)
{
  const float* pred_cls  = (const float*)d_in[0];
  const float* pred_bbox = (const float*)d_in[1];
  const float* anchors   = (const float*)d_in[2];
  const int*   gt_cls    = (const int*)  d_in[3];
  const float* gt_bbox   = (const float*)d_in[4];
  const float* mask_gt   = (const float*)d_in[5];

  // ws layout:
  //   topkeys    : B*M*13 u64      @ 0        (53248 B)
  //   pos_align  : B*M u32(float)  @ 53248    (2048 B)
  //   pos_ovl    : B*M u32(float)  @ 55296    (2048 B)
  //   anchor_m   : B*A i32         @ 57344    (537600 B)
  //   anchor_al  : B*A f32         @ 594944   (537600 B)
  // total 1132544 B (~1.1 MB)
  char* ws = (char*)d_ws;
  unsigned long long* topkeys = (unsigned long long*)(ws);
  unsigned int* pos_align = (unsigned int*)(ws + 53248);
  unsigned int* pos_ovl   = (unsigned int*)(ws + 55296);
  int*   anchor_m  = (int*)  (ws + 57344);
  float* anchor_al = (float*)(ws + 594944);

  float* out_cls  = (float*)d_out;
  float* out_bbox = out_cls + (size_t)BB*AA*CC;
  float* out_fg   = out_bbox + (size_t)BB*AA*4;

  k_topk<<<dim3(MM, BB), 512, 0, stream>>>(
      pred_cls, pred_bbox, anchors, gt_cls, gt_bbox, mask_gt,
      topkeys, pos_align, pos_ovl);
  k_resolve<<<dim3(BB*17), 512, 0, stream>>>(
      pred_cls, pred_bbox, anchors, gt_cls, gt_bbox, mask_gt, topkeys,
      out_bbox, out_fg, anchor_m, anchor_al, pos_align, pos_ovl);
  k_cls<<<(BB*AA*(CC/4) + 255)/256, 256, 0, stream>>>(
      anchor_m, anchor_al, pos_align, pos_ovl, gt_cls, out_cls);
}